// Round 6
// baseline (708.302 us; speedup 1.0000x reference)
//
#include <hip/hip_runtime.h>

// Fixed problem dims from setup_inputs(): b=16, L=256, h=256, eh=64, M=N=128.
// Output layout (flat float32, element offsets):
//   X1      @ 0           (16,256,256)   = 1,048,576
//   X2      @ 1,048,576   (16,256,256)
//   E1      @ 2,097,152   (16,256,256,64)= 67,108,864
//   E2      @ 69,206,016  (16,256,256,64)
//   A1      @ 136,314,880 (16,256,256)
//   A2      @ 137,363,456 (16,256,256)
//   mask1   @ 138,412,032 (16,256,256)
//   mask2   @ 139,460,608 (16,256,256)
//   w1      @ 140,509,184 (16,256,1)     = 4,096
//   w2      @ 140,513,280 (16,256,1)
//   mask_out@ 140,517,376 (16,256,256)
// total 141,565,952 elements = 566 MB mandatory writes.
//
// Round 6 structure: ROW-CONTIGUOUS single pass, ONE launch.
// Key observation: for each E1/E2 output row (i,p), the valid region is ONE
// contiguous q-range [q0,q1) (row layout is [q][ch], 256 B per q), and its
// source is an equally contiguous range of one source row. So each row is
//   zeros[0:q0) | memcpy | zeros[q1:256)
// -> every output byte written exactly once, stores fully unconditional and
// sequential (fill-like), loads contiguous. 16 independent ld/st pairs per
// thread for fill-kernel-grade ILP.
//
//   E1 row p: p<l0    -> q:[0,l0),   src row p,        src q0 = 0
//             p<2l0   -> q:[l0,2l0), src row p-l0,     src q0 = 0
//             else    -> all zeros
//   E2 row p: p<l1    -> q:[0,l1),   src row l0+p,     src q0 = l0
//             p<2l1   -> q:[l1,2l1), src row l0+p-l1,  src q0 = l0
//             else    -> all zeros
//   (max src row/col = l0+l1-1 <= 255 -> no clamp needed)

#define OFF_X1   0
#define OFF_X2   1048576
#define OFF_E1   2097152
#define OFF_E2   69206016
#define OFF_A1   136314880
#define OFF_A2   137363456
#define OFF_M1   138412032
#define OFF_M2   139460608
#define OFF_W1   140509184
#define OFF_MO   140517376

#define OFF_E1_V4 (OFF_E1 / 4)   //   524,288 float4
#define OFF_E2_V4 (OFF_E2 / 4)   // 17,301,504 float4

// clang ext-vector type: __builtin_nontemporal_store accepts this (HIP's
// float4 struct is rejected by the builtin's type check).
typedef float f32x4 __attribute__((ext_vector_type(4)));

// Grid: 12,288 blocks x 256 threads.
//   blocks [0, 8192):     E rows. bb = which*4096 + i*256 + p. One block
//                         writes one 64 KB output row (4096 float4; 16/thread).
//   blocks [8192, 12288): small outputs. s = bb-8192 = is*256 + ps; qs = tid.
__global__ __launch_bounds__(256) void fused_row_kernel(
    const f32x4* __restrict__ E,        // (16,256,256,16) float4
    const float* __restrict__ X,        // (16,256,256)
    const float* __restrict__ A,        // (16,256,256)
    const int*   __restrict__ mask,     // (16,256,256) bool as 4-byte elems
    const int*   __restrict__ mol_lens, // (16,2)
    float*       __restrict__ out)
{
    const int bb  = blockIdx.x;
    const int tid = threadIdx.x;

    f32x4* outv4 = (f32x4*)out;
    const f32x4 zero = (f32x4)(0.f, 0.f, 0.f, 0.f);

    if (bb < 8192) {
        // ---------------- E rows ----------------
        const int which = bb >> 12;          // 0 -> E1, 1 -> E2 (block-uniform)
        const int i     = (bb >> 8) & 15;    // block-uniform
        const int p     = bb & 255;          // block-uniform

        const int l0 = mol_lens[i * 2];      // scalar loads
        const int l1 = mol_lens[i * 2 + 1];

        int q0 = 1, q1 = 0, srow = 0, sq0 = 0;   // default: empty (all-zero row)
        if (!which) {
            if (p < l0)          { q0 = 0;  q1 = l0;     srow = p;            sq0 = 0; }
            else if (p < 2 * l0) { q0 = l0; q1 = 2 * l0; srow = p - l0;       sq0 = 0; }
        } else {
            if (p < l1)          { q0 = 0;  q1 = l1;     srow = l0 + p;       sq0 = l0; }
            else if (p < 2 * l1) { q0 = l1; q1 = 2 * l1; srow = l0 + p - l1;  sq0 = l0; }
        }

        // out row base (float4): OFF + (i*256+p)*4096
        const int out_base = (which ? OFF_E2_V4 : OFF_E1_V4) + (bb & 4095) * 4096;
        // src base (float4): valid lane q reads src element (q - q0 + sq0)
        // src_f4 = ((i*256+srow)*256 + sq0 - q0)*16 + f4   (column index >= 0
        // whenever q >= q0, so the dereferenced address is always in-bounds)
        const int src_base = ((i * 256 + srow) * 256 + sq0 - q0) * 16;

        #pragma unroll
        for (int it = 0; it < 16; ++it) {
            const int f4 = it * 256 + tid;   // 0..4095 within the row
            const int q  = f4 >> 4;
            f32x4 v = zero;
            if (q >= q0 && q < q1)
                v = E[src_base + f4];
            __builtin_nontemporal_store(v, &outv4[out_base + f4]);
        }
    } else {
        // ---------------- small outputs ----------------
        const int s   = bb - 8192;           // 0..4095
        const int qs  = tid;                 // per-lane
        const int ps  = s & 255;             // block-uniform
        const int is  = s >> 8;              // block-uniform
        const int ts  = s * 256 + tid;       // 0 .. 1,048,575

        const int sl0 = mol_lens[is * 2];
        const int sl1 = mol_lens[is * 2 + 1];

        // X1
        const bool v1  = ps < 2 * sl0;
        const int  s1p = (ps < sl0) ? ps : ps - sl0;
        __builtin_nontemporal_store(
            v1 ? X[(is * 256 + s1p) * 256 + qs] : 0.f, &out[OFF_X1 + ts]);

        // X2
        const bool v2  = ps < 2 * sl1;
        const int  s2p = (ps < sl1) ? ps : ps - sl1;
        __builtin_nontemporal_store(
            v2 ? X[(is * 256 + s2p) * 256 + qs] : 0.f, &out[OFF_X2 + ts]);

        // A1 / mask1
        const bool f1p = ps < sl0, s1pb = (!f1p) && v1;
        const bool f1q = qs < sl0, s1qb = (!f1q) && (qs < 2 * sl0);
        const int  s1q = f1q ? qs : qs - sl0;
        const bool blk1 = (f1p && f1q) || (s1pb && s1qb);
        __builtin_nontemporal_store(
            blk1 ? A[(is * 256 + s1p) * 256 + s1q] : 0.f, &out[OFF_A1 + ts]);
        __builtin_nontemporal_store(
            ((f1p && s1qb) || (s1pb && f1q)) ? 0.f : 1.f, &out[OFF_M1 + ts]);

        // A2 / mask2
        const bool f2p = ps < sl1, s2pb = (!f2p) && v2;
        const bool f2q = qs < sl1, s2qb = (!f2q) && (qs < 2 * sl1);
        int e2p = sl0 + (f2p ? ps : ps - sl1); if (e2p > 255) e2p = 255;
        int e2q = sl0 + (f2q ? qs : qs - sl1); if (e2q > 255) e2q = 255;
        const bool blk2 = (f2p && f2q) || (s2pb && s2qb);
        __builtin_nontemporal_store(
            blk2 ? A[(is * 256 + e2p) * 256 + e2q] : 0.f, &out[OFF_A2 + ts]);
        __builtin_nontemporal_store(
            ((f2p && s2qb) || (s2pb && f2q)) ? 0.f : 1.f, &out[OFF_M2 + ts]);

        // mask_out
        const bool leftp = ps < sl0, leftq = qs < sl0;
        const int  lsum  = sl0 + sl1;
        const bool middp = (!leftp) && (ps < lsum);
        const bool middq = (!leftq) && (qs < lsum);
        const bool ct = (leftp && leftq) || ((!leftp) && (!leftq));
        const bool cf = (leftp && middq) || (middp && leftq);
        float mv;
        if (ct)      mv = 1.f;
        else if (cf) mv = 0.f;
        else         mv = (mask[ts] != 0) ? 1.f : 0.f;
        __builtin_nontemporal_store(mv, &out[OFF_MO + ts]);

        // w1/w2 zeros: first 8192 small threads (s < 32)
        if (ts < 8192)
            __builtin_nontemporal_store(0.f, &out[OFF_W1 + ts]);
    }
}

extern "C" void kernel_launch(void* const* d_in, const int* in_sizes, int n_in,
                              void* d_out, int out_size, void* d_ws, size_t ws_size,
                              hipStream_t stream) {
    const float* X        = (const float*)d_in[0];
    const float* E        = (const float*)d_in[1];
    const float* A        = (const float*)d_in[2];
    // d_in[3] = w (unused: w1/w2 are zeros)
    const int*   mask     = (const int*)d_in[4];
    const int*   mol_lens = (const int*)d_in[5];
    // d_in[6]=M, d_in[7]=N — compile-time known (128)

    float* out = (float*)d_out;

    fused_row_kernel<<<12288, 256, 0, stream>>>(
        (const f32x4*)E, X, A, mask, mol_lens, out);
}